// Round 11
// baseline (107.176 us; speedup 1.0000x reference)
//
#include <hip/hip_runtime.h>
#include <math.h>

#define N_SAMPLES 8192
#define DIM 128
#define NCLS 1024
#define MARGIN_V 0.3f
#define DIST_GX (N_SAMPLES / 128)   // 64 j-tiles of 128
#define DIST_GY (NCLS / 128)        // 8 class-tiles of 128
#define NPART DIST_GX               // 64 partials per class (j-halves merged in LDS)
#define MAXMEM 64                   // LDS member-list capacity per class
#define PIPE 16                     // pipelined gather depth

using bf16x8 = __attribute__((ext_vector_type(8))) short;
using f32x16 = __attribute__((ext_vector_type(16))) float;

__device__ __forceinline__ short bf16_rne(float x) {
  unsigned u = __float_as_uint(x);
  unsigned r = u + 0x7FFFu + ((u >> 16) & 1u);
  return (short)(r >> 16);
}

// K1: centers only. 512 blocks, 2 classes each: scan targets into LDS member
// lists, gather-sum rows (pipelined), write fp32 centers + counts.
// Block 0 zeroes out[0..1] (finalize atomicAdd targets).
__global__ __launch_bounds__(256) void centers_kernel(
    const float* __restrict__ inputs, const int* __restrict__ targets,
    float* __restrict__ centers, int* __restrict__ counts,
    float* __restrict__ out) {
  __shared__ int mem[2][MAXMEM];
  __shared__ int mcnt[2];
  int b = blockIdx.x;
  int tid = threadIdx.x;
  if (b == 0 && tid < 2) out[tid] = 0.f;
  int c0 = b * 2;
  if (tid < 2) { mcnt[tid] = 0; mem[tid][0] = 0; }  // mem[.][0] valid even if cnt==0
  __syncthreads();
  #pragma unroll
  for (int i = 0; i < N_SAMPLES / 256; i++) {
    int idx = tid + 256 * i;
    int tg = targets[idx];
    if (tg == c0) {
      int p = atomicAdd(&mcnt[0], 1);
      if (p < MAXMEM) mem[0][p] = idx;
    } else if (tg == c0 + 1) {
      int p = atomicAdd(&mcnt[1], 1);
      if (p < MAXMEM) mem[1][p] = idx;
    }
  }
  __syncthreads();
  int half = tid >> 7;
  int c = c0 + half;
  int d = tid & 127;
  int cnt = mcnt[half];
  int cl = (cnt < MAXMEM) ? cnt : MAXMEM;
  int n1 = (cl < PIPE) ? cl : PIPE;
  int idxs[PIPE];
  #pragma unroll
  for (int i = 0; i < PIPE; i++) idxs[i] = mem[half][(i < n1) ? i : 0];
  float vbuf[PIPE];
  #pragma unroll
  for (int i = 0; i < PIPE; i++) vbuf[i] = inputs[(size_t)idxs[i] * DIM + d];
  float acc = 0.f;
  #pragma unroll
  for (int i = 0; i < PIPE; i++) if (i < n1) acc += vbuf[i];
  for (int m = PIPE; m < cl; m++) acc += inputs[(size_t)mem[half][m] * DIM + d];
  float ctr = (cnt > 0) ? acc / (float)cnt : 0.f;
  centers[(size_t)c * DIM + d] = ctr;
  if (d == 0) counts[c] = cnt;
}

// K2: MFMA dist (128x128 tile, 4 waves of 64x64 = 2x2 32x32x16), bf16.
// Fragments assembled IN-REGISTER from raw fp32 (no packed operands):
//   operand[row=lane&31][k=(lane>>5)*8+j], dims k = ks*16+(lane>>5)*8+{0..7}
//   -> two dwordx4 loads + 8 bf16 converts per fragment (layout verified
//   R1-R10). x2/c2 computed from the same fp32 values: per-lane half-row
//   sum of squares + shfl_xor(32) combine (exact fp32).
// Epilogue unchanged: per-class max/min, j-half merge in LDS, plain stores.
__global__ __launch_bounds__(256) void dist_kernel(
    const float* __restrict__ inputs, const float* __restrict__ centers,
    const int* __restrict__ targets,
    float* __restrict__ dp_part, float* __restrict__ dn_part) {
  __shared__ float sc2[128];
  __shared__ int stgt[128];
  __shared__ float redp[4][64];
  __shared__ float redn[4][64];

  int tid = threadIdx.x;
  int jbase = blockIdx.x * 128;
  int cbase = blockIdx.y * 128;
  int wave = tid >> 6, lane = tid & 63;
  int wm = wave >> 1, wn = wave & 1;
  int col = lane & 31;
  int halfk = (lane >> 5) * 8;  // dim sub-offset within 16-wide k-step

  if (tid < 128) stgt[tid] = targets[jbase + tid];

  // ---- A fragments (centers) + c2 partials ----
  bf16x8 a[2][8], b[2][8];
  float c2p[2] = {0.f, 0.f};
  #pragma unroll
  for (int mt = 0; mt < 2; mt++) {
    const float* arow = centers + (size_t)(cbase + wm * 64 + mt * 32 + col) * DIM + halfk;
    #pragma unroll
    for (int ks = 0; ks < 8; ks++) {
      float4 u0 = *(const float4*)(arow + ks * 16);
      float4 u1 = *(const float4*)(arow + ks * 16 + 4);
      float v[8] = {u0.x, u0.y, u0.z, u0.w, u1.x, u1.y, u1.z, u1.w};
      bf16x8 h;
      #pragma unroll
      for (int i = 0; i < 8; i++) {
        h[i] = bf16_rne(v[i]);
        c2p[mt] += v[i] * v[i];
      }
      a[mt][ks] = h;
    }
  }
  // ---- B fragments (inputs) + x2 partials ----
  float x2p[2] = {0.f, 0.f};
  #pragma unroll
  for (int nt = 0; nt < 2; nt++) {
    const float* brow = inputs + (size_t)(jbase + wn * 64 + nt * 32 + col) * DIM + halfk;
    #pragma unroll
    for (int ks = 0; ks < 8; ks++) {
      float4 u0 = *(const float4*)(brow + ks * 16);
      float4 u1 = *(const float4*)(brow + ks * 16 + 4);
      float v[8] = {u0.x, u0.y, u0.z, u0.w, u1.x, u1.y, u1.z, u1.w};
      bf16x8 h;
      #pragma unroll
      for (int i = 0; i < 8; i++) {
        h[i] = bf16_rne(v[i]);
        x2p[nt] += v[i] * v[i];
      }
      b[nt][ks] = h;
    }
  }
  // combine halves: lane l and l^32 hold complementary 64-dim partials of
  // the same column
  float x2v[2];
  #pragma unroll
  for (int mt = 0; mt < 2; mt++) c2p[mt] += __shfl_xor(c2p[mt], 32);
  #pragma unroll
  for (int nt = 0; nt < 2; nt++) x2v[nt] = x2p[nt] + __shfl_xor(x2p[nt], 32);
  // c2 -> LDS (epilogue needs row-spread indexing); wn-duplicate writes are
  // benign (identical values)
  if (lane < 32) {
    sc2[wm * 64 + col] = c2p[0];
    sc2[wm * 64 + 32 + col] = c2p[1];
  }

  f32x16 acc[2][2];
  #pragma unroll
  for (int i = 0; i < 2; i++)
    #pragma unroll
    for (int j = 0; j < 2; j++)
      acc[i][j] = (f32x16)(0.f);

  #pragma unroll
  for (int ks = 0; ks < 8; ks++)
    #pragma unroll
    for (int mt = 0; mt < 2; mt++)
      #pragma unroll
      for (int nt = 0; nt < 2; nt++)
        acc[mt][nt] = __builtin_amdgcn_mfma_f32_32x32x16_bf16(a[mt][ks], b[nt][ks], acc[mt][nt], 0, 0, 0);

  __syncthreads();  // sc2/stgt visible

  int hf = lane >> 5;
  #pragma unroll
  for (int mt = 0; mt < 2; mt++) {
    #pragma unroll
    for (int r = 0; r < 16; r++) {
      int rowl = (r & 3) + 8 * (r >> 2) + 4 * hf;
      int c_loc = wm * 64 + mt * 32 + rowl;
      int cg = cbase + c_loc;
      float c2v = sc2[c_loc];
      float pmax = -INFINITY, nmin = INFINITY;
      #pragma unroll
      for (int nt = 0; nt < 2; nt++) {
        int j_loc = wn * 64 + nt * 32 + col;
        float d2 = c2v + x2v[nt] - 2.f * acc[mt][nt][r];
        if (stgt[j_loc] == cg) pmax = fmaxf(pmax, d2);
        else                   nmin = fminf(nmin, d2);
      }
      #pragma unroll
      for (int m = 1; m < 32; m <<= 1) {
        pmax = fmaxf(pmax, __shfl_xor(pmax, m));
        nmin = fminf(nmin, __shfl_xor(nmin, m));
      }
      if (col == 0) {
        redp[wave][mt * 32 + rowl] = pmax;
        redn[wave][mt * 32 + rowl] = nmin;
      }
    }
  }
  __syncthreads();
  if (tid < 128) {
    int wmx = tid >> 6, idx = tid & 63;
    float dp = fmaxf(redp[wmx * 2][idx], redp[wmx * 2 + 1][idx]);
    float dn = fminf(redn[wmx * 2][idx], redn[wmx * 2 + 1][idx]);
    size_t slot = (size_t)blockIdx.x * NCLS + cbase + tid;
    dp_part[slot] = dp;
    dn_part[slot] = dn;
  }
}

// K3: 16 blocks x 256 threads. Block g owns 64 classes; 4 p-groups x 16
// partials each, coalesced reads, LDS combine, weighted wave reduce, one
// atomicAdd pair per block into out (zeroed by K1).
__global__ __launch_bounds__(256) void finalize_kernel(
    const float* __restrict__ dp_part, const float* __restrict__ dn_part,
    const int* __restrict__ counts, float* __restrict__ out) {
  __shared__ float sdp[4][64];
  __shared__ float sdn[4][64];
  int g = blockIdx.x;
  int t = threadIdx.x;
  int cl = t & 63;
  int pg = t >> 6;
  int c = g * 64 + cl;
  float dp = -INFINITY, dn = INFINITY;
  #pragma unroll
  for (int p = pg * 16; p < pg * 16 + 16; p++) {
    dp = fmaxf(dp, dp_part[(size_t)p * NCLS + c]);
    dn = fminf(dn, dn_part[(size_t)p * NCLS + c]);
  }
  sdp[pg][cl] = dp;
  sdn[pg][cl] = dn;
  __syncthreads();
  if (t < 64) {  // wave 0
    dp = fmaxf(fmaxf(sdp[0][cl], sdp[1][cl]), fmaxf(sdp[2][cl], sdp[3][cl]));
    dn = fminf(fminf(sdn[0][cl], sdn[1][cl]), fminf(sdn[2][cl], sdn[3][cl]));
    int cnt = counts[c];
    float ls = 0.f, ps = 0.f;
    if (cnt > 0) {
      ls = (float)cnt * fmaxf(dp - dn + MARGIN_V, 0.f);
      ps = (float)cnt * ((dn > dp) ? 1.f : 0.f);
    }
    #pragma unroll
    for (int sh = 32; sh > 0; sh >>= 1) {
      ls += __shfl_down(ls, sh);
      ps += __shfl_down(ps, sh);
    }
    if (t == 0) {
      atomicAdd(&out[0], ls / (float)N_SAMPLES);
      atomicAdd(&out[1], ps / (float)N_SAMPLES);
    }
  }
}

extern "C" void kernel_launch(void* const* d_in, const int* in_sizes, int n_in,
                              void* d_out, int out_size, void* d_ws, size_t ws_size,
                              hipStream_t stream) {
  const float* inputs = (const float*)d_in[0];
  const int* targets = (const int*)d_in[1];
  float* out = (float*)d_out;

  char* w = (char*)d_ws;
  float* centers = (float*)w;       w += (size_t)NCLS * DIM * 4;      // 512 KB
  int* counts = (int*)w;            w += (size_t)NCLS * 4;
  float* dp_part = (float*)w;       w += (size_t)NPART * NCLS * 4;    // 256 KB
  float* dn_part = (float*)w;       w += (size_t)NPART * NCLS * 4;    // 256 KB

  centers_kernel<<<NCLS / 2, 256, 0, stream>>>(inputs, targets, centers, counts, out);
  dist_kernel<<<dim3(DIST_GX, DIST_GY), 256, 0, stream>>>(
      inputs, centers, targets, dp_part, dn_part);
  finalize_kernel<<<16, 256, 0, stream>>>(dp_part, dn_part, counts, out);
}

// Round 12
// 84.304 us; speedup vs baseline: 1.2713x; 1.2713x over previous
//
#include <hip/hip_runtime.h>
#include <math.h>

#define N_SAMPLES 8192
#define DIM 128
#define NCLS 1024
#define MARGIN_V 0.3f
#define DIST_GX (N_SAMPLES / 128)   // 64 j-tiles of 128
#define DIST_GY (NCLS / 128)        // 8 class-tiles of 128
#define NPART DIST_GX               // 64 partials per class (j-halves merged in LDS)
#define MAXMEM 64                   // LDS member-list capacity per class
#define PIPE 16                     // pipelined gather depth (covers P(cnt<=16)~0.997)

using bf16x8 = __attribute__((ext_vector_type(8))) short;
using f32x16 = __attribute__((ext_vector_type(16))) float;
using short8 = __attribute__((ext_vector_type(8))) short;

__device__ __forceinline__ short bf16_rne(float x) {
  unsigned u = __float_as_uint(x);
  unsigned r = u + 0x7FFFu + ((u >> 16) & 1u);
  return (short)(r >> 16);
}

// Packed fragment layout, single bf16 plane (row-major source [row][k]):
//   tile = row>>5, kstep = oct>>1 (oct = k/8), lane = ((oct&1)<<5)|(row&31)
//   short8 index = (tile*8 + kstep)*64 + lane
// Matches mfma_32x32x16 A/B operand layout operand[row=lane&31][k=(lane>>5)*8+j]
// (verified R1-R10; bf16-only passes with absmax ~0).
// NOTE (R11 lesson): keep the packed round-trip. In-register assembly from
// row-major fp32 makes each lane read a different 512B-strided row -> 64
// cache lines per wave-load instead of 1 contiguous KB; dist went 6 -> 40 µs.
__device__ __forceinline__ size_t frag_idx(int row, int oct) {
  int tile = row >> 5, ks = oct >> 1, lane = ((oct & 1) << 5) | (row & 31);
  return (size_t)(tile * 8 + ks) * 64 + lane;
}

// K1: fused pack.
// Blocks [0,512): B-side — x2 + bf16 pack of 16 input rows.
// Blocks [512,1024): A-side — 2 classes/block: scan targets into LDS member
// lists, gather-sum center (pipelined: 16 independent row loads in flight),
// c2, counts, bf16 pack. Block 0 zeroes out[0..1].
__global__ __launch_bounds__(256) void pack_kernel(
    const float* __restrict__ inputs, const int* __restrict__ targets,
    float* __restrict__ x2, float* __restrict__ c2, int* __restrict__ counts,
    short8* __restrict__ Apk, short8* __restrict__ Bpk, float* __restrict__ out) {
  int b = blockIdx.x;
  int tid = threadIdx.x;
  if (b == 0 && tid < 2) out[tid] = 0.f;
  if (b < N_SAMPLES / 16) {
    int row = b * 16 + (tid >> 4);
    int oct = tid & 15;
    const float4* p = (const float4*)(inputs + (size_t)row * DIM + oct * 8);
    float4 v0 = p[0], v1 = p[1];
    float v[8] = {v0.x, v0.y, v0.z, v0.w, v1.x, v1.y, v1.z, v1.w};
    float s = 0.f;
    #pragma unroll
    for (int i = 0; i < 8; i++) s += v[i] * v[i];
    #pragma unroll
    for (int m = 1; m < 16; m <<= 1) s += __shfl_xor(s, m);
    if (oct == 0) x2[row] = s;
    short8 hi;
    #pragma unroll
    for (int i = 0; i < 8; i++) hi[i] = bf16_rne(v[i]);
    Bpk[frag_idx(row, oct)] = hi;
  } else {
    __shared__ int mem[2][MAXMEM];
    __shared__ int mcnt[2];
    __shared__ float sctr[2][128];
    __shared__ float wsum[4];
    int c0 = (b - N_SAMPLES / 16) * 2;
    if (tid < 2) { mcnt[tid] = 0; mem[tid][0] = 0; }  // mem[.][0] valid even if cnt==0
    __syncthreads();
    #pragma unroll
    for (int i = 0; i < N_SAMPLES / 256; i++) {
      int idx = tid + 256 * i;
      int tg = targets[idx];
      if (tg == c0) {
        int p = atomicAdd(&mcnt[0], 1);
        if (p < MAXMEM) mem[0][p] = idx;
      } else if (tg == c0 + 1) {
        int p = atomicAdd(&mcnt[1], 1);
        if (p < MAXMEM) mem[1][p] = idx;
      }
    }
    __syncthreads();
    int half = tid >> 7;
    int c = c0 + half;
    int d = tid & 127;
    int cnt = mcnt[half];
    int cl = (cnt < MAXMEM) ? cnt : MAXMEM;
    int n1 = (cl < PIPE) ? cl : PIPE;
    // pipelined gather: indices first, then all row loads independent
    int idxs[PIPE];
    #pragma unroll
    for (int i = 0; i < PIPE; i++) idxs[i] = mem[half][(i < n1) ? i : 0];
    float vbuf[PIPE];
    #pragma unroll
    for (int i = 0; i < PIPE; i++) vbuf[i] = inputs[(size_t)idxs[i] * DIM + d];
    float acc = 0.f;
    #pragma unroll
    for (int i = 0; i < PIPE; i++) if (i < n1) acc += vbuf[i];
    for (int m = PIPE; m < cl; m++) acc += inputs[(size_t)mem[half][m] * DIM + d];
    float ctr = (cnt > 0) ? acc / (float)cnt : 0.f;
    sctr[half][d] = ctr;
    float vv = ctr * ctr;
    #pragma unroll
    for (int sh = 32; sh > 0; sh >>= 1) vv += __shfl_down(vv, sh);
    if ((tid & 63) == 0) wsum[tid >> 6] = vv;
    __syncthreads();
    if (d == 0) {
      c2[c] = wsum[half * 2] + wsum[half * 2 + 1];
      counts[c] = cnt;
    }
    if (d < 16) {
      int oct = d;
      short8 hi;
      #pragma unroll
      for (int i = 0; i < 8; i++) hi[i] = bf16_rne(sctr[half][oct * 8 + i]);
      Apk[frag_idx(c, oct)] = hi;
    }
  }
}

// K2: MFMA dist (128x128 tile, 4 waves of 64x64 = 2x2 32x32x16), pure bf16.
// Full fragment prefetch: all 32 loads (a[2][8], b[2][8]) issued before the
// MFMA chain — one latency exposure instead of ~4. Grid caps occupancy at
// 2 blocks/CU anyway, so the ~210 VGPRs are free.
__global__ __launch_bounds__(256) void dist_kernel(
    const short8* __restrict__ Apk, const short8* __restrict__ Bpk,
    const float* __restrict__ x2, const float* __restrict__ c2,
    const int* __restrict__ targets,
    float* __restrict__ dp_part, float* __restrict__ dn_part) {
  __shared__ float sc2[128];
  __shared__ float sx2[128];
  __shared__ int stgt[128];
  __shared__ float redp[4][64];
  __shared__ float redn[4][64];

  int tid = threadIdx.x;
  int jbase = blockIdx.x * 128;
  int cbase = blockIdx.y * 128;
  int wave = tid >> 6, lane = tid & 63;
  int wm = wave >> 1, wn = wave & 1;

  if (tid < 128) {
    sc2[tid] = c2[cbase + tid];
    sx2[tid] = x2[jbase + tid];
    stgt[tid] = targets[jbase + tid];
  }

  int mtg0 = (cbase >> 5) + wm * 2;
  int ntg0 = (jbase >> 5) + wn * 2;

  // prefetch ALL fragments (32 x 16B per lane)
  bf16x8 a[2][8], b[2][8];
  #pragma unroll
  for (int ks = 0; ks < 8; ks++)
    #pragma unroll
    for (int mt = 0; mt < 2; mt++)
      a[mt][ks] = Apk[(size_t)((mtg0 + mt) * 8 + ks) * 64 + lane];
  #pragma unroll
  for (int ks = 0; ks < 8; ks++)
    #pragma unroll
    for (int nt = 0; nt < 2; nt++)
      b[nt][ks] = Bpk[(size_t)((ntg0 + nt) * 8 + ks) * 64 + lane];

  f32x16 acc[2][2];
  #pragma unroll
  for (int i = 0; i < 2; i++)
    #pragma unroll
    for (int j = 0; j < 2; j++)
      acc[i][j] = (f32x16)(0.f);

  #pragma unroll
  for (int ks = 0; ks < 8; ks++)
    #pragma unroll
    for (int mt = 0; mt < 2; mt++)
      #pragma unroll
      for (int nt = 0; nt < 2; nt++)
        acc[mt][nt] = __builtin_amdgcn_mfma_f32_32x32x16_bf16(a[mt][ks], b[nt][ks], acc[mt][nt], 0, 0, 0);

  __syncthreads();  // staging visible

  int hf = lane >> 5;
  int col = lane & 31;
  #pragma unroll
  for (int mt = 0; mt < 2; mt++) {
    #pragma unroll
    for (int r = 0; r < 16; r++) {
      int rowl = (r & 3) + 8 * (r >> 2) + 4 * hf;
      int c_loc = wm * 64 + mt * 32 + rowl;
      int cg = cbase + c_loc;
      float c2v = sc2[c_loc];
      float pmax = -INFINITY, nmin = INFINITY;
      #pragma unroll
      for (int nt = 0; nt < 2; nt++) {
        int j_loc = wn * 64 + nt * 32 + col;
        float d2 = c2v + sx2[j_loc] - 2.f * acc[mt][nt][r];
        if (stgt[j_loc] == cg) pmax = fmaxf(pmax, d2);
        else                   nmin = fminf(nmin, d2);
      }
      #pragma unroll
      for (int m = 1; m < 32; m <<= 1) {
        pmax = fmaxf(pmax, __shfl_xor(pmax, m));
        nmin = fminf(nmin, __shfl_xor(nmin, m));
      }
      if (col == 0) {
        redp[wave][mt * 32 + rowl] = pmax;
        redn[wave][mt * 32 + rowl] = nmin;
      }
    }
  }
  __syncthreads();
  if (tid < 128) {
    int wmx = tid >> 6, idx = tid & 63;
    float dp = fmaxf(redp[wmx * 2][idx], redp[wmx * 2 + 1][idx]);
    float dn = fminf(redn[wmx * 2][idx], redn[wmx * 2 + 1][idx]);
    size_t slot = (size_t)blockIdx.x * NCLS + cbase + tid;
    dp_part[slot] = dp;
    dn_part[slot] = dn;
  }
}

// K3: 16 blocks x 256 threads. Block g owns 64 classes; 4 p-groups x 16
// partials each, coalesced reads (32 KB/block), LDS combine, weighted wave
// reduce, one atomicAdd pair per block into out (zeroed by K1).
__global__ __launch_bounds__(256) void finalize_kernel(
    const float* __restrict__ dp_part, const float* __restrict__ dn_part,
    const int* __restrict__ counts, float* __restrict__ out) {
  __shared__ float sdp[4][64];
  __shared__ float sdn[4][64];
  int g = blockIdx.x;
  int t = threadIdx.x;
  int cl = t & 63;
  int pg = t >> 6;
  int c = g * 64 + cl;
  float dp = -INFINITY, dn = INFINITY;
  #pragma unroll
  for (int p = pg * 16; p < pg * 16 + 16; p++) {
    dp = fmaxf(dp, dp_part[(size_t)p * NCLS + c]);
    dn = fminf(dn, dn_part[(size_t)p * NCLS + c]);
  }
  sdp[pg][cl] = dp;
  sdn[pg][cl] = dn;
  __syncthreads();
  if (t < 64) {  // wave 0
    dp = fmaxf(fmaxf(sdp[0][cl], sdp[1][cl]), fmaxf(sdp[2][cl], sdp[3][cl]));
    dn = fminf(fminf(sdn[0][cl], sdn[1][cl]), fminf(sdn[2][cl], sdn[3][cl]));
    int cnt = counts[c];
    float ls = 0.f, ps = 0.f;
    if (cnt > 0) {
      ls = (float)cnt * fmaxf(dp - dn + MARGIN_V, 0.f);
      ps = (float)cnt * ((dn > dp) ? 1.f : 0.f);
    }
    #pragma unroll
    for (int sh = 32; sh > 0; sh >>= 1) {
      ls += __shfl_down(ls, sh);
      ps += __shfl_down(ps, sh);
    }
    if (t == 0) {
      atomicAdd(&out[0], ls / (float)N_SAMPLES);
      atomicAdd(&out[1], ps / (float)N_SAMPLES);
    }
  }
}

extern "C" void kernel_launch(void* const* d_in, const int* in_sizes, int n_in,
                              void* d_out, int out_size, void* d_ws, size_t ws_size,
                              hipStream_t stream) {
  const float* inputs = (const float*)d_in[0];
  const int* targets = (const int*)d_in[1];
  float* out = (float*)d_out;

  char* w = (char*)d_ws;
  float* x2 = (float*)w;            w += (size_t)N_SAMPLES * 4;
  float* c2 = (float*)w;            w += (size_t)NCLS * 4;
  int* counts = (int*)w;            w += (size_t)NCLS * 4;
  float* dp_part = (float*)w;       w += (size_t)NPART * NCLS * 4;    // 256 KB
  float* dn_part = (float*)w;       w += (size_t)NPART * NCLS * 4;    // 256 KB
  short8* Apk = (short8*)w;         w += (size_t)NCLS * DIM * 2;      // 256 KB
  short8* Bpk = (short8*)w;         w += (size_t)N_SAMPLES * DIM * 2; // 2 MB

  pack_kernel<<<N_SAMPLES / 16 + NCLS / 2, 256, 0, stream>>>(
      inputs, targets, x2, c2, counts, Apk, Bpk, out);
  dist_kernel<<<dim3(DIST_GX, DIST_GY), 256, 0, stream>>>(
      Apk, Bpk, x2, c2, targets, dp_part, dn_part);
  finalize_kernel<<<16, 256, 0, stream>>>(dp_part, dn_part, counts, out);
}

// Round 13
// 76.776 us; speedup vs baseline: 1.3960x; 1.0980x over previous
//
#include <hip/hip_runtime.h>
#include <math.h>

#define N_SAMPLES 8192
#define DIM 128
#define NCLS 1024
#define MARGIN_V 0.3f
#define DIST_GX (N_SAMPLES / 128)   // 64 j-tiles of 128
#define DIST_GY (NCLS / 64)         // 16 class-tiles of 64 (4 blocks/CU)
#define NPART DIST_GX               // 64 partials per class (j-halves merged in LDS)
#define MAXMEM 64                   // LDS member-list capacity per class
#define PIPE 16                     // pipelined gather depth (covers P(cnt<=16)~0.997)

using bf16x8 = __attribute__((ext_vector_type(8))) short;
using f32x16 = __attribute__((ext_vector_type(16))) float;
using short8 = __attribute__((ext_vector_type(8))) short;

__device__ __forceinline__ short bf16_rne(float x) {
  unsigned u = __float_as_uint(x);
  unsigned r = u + 0x7FFFu + ((u >> 16) & 1u);
  return (short)(r >> 16);
}

// Packed fragment layout, single bf16 plane (row-major source [row][k]):
//   tile = row>>5, kstep = oct>>1 (oct = k/8), lane = ((oct&1)<<5)|(row&31)
//   short8 index = (tile*8 + kstep)*64 + lane
// Matches mfma_32x32x16 A/B operand layout operand[row=lane&31][k=(lane>>5)*8+j]
// (verified R1-R12; bf16-only passes with absmax ~0).
// NOTE (R11 lesson): keep the packed round-trip — in-register assembly from
// row-major fp32 reads 64 cache lines per wave-load instead of 1 (dist 6->40us).
__device__ __forceinline__ size_t frag_idx(int row, int oct) {
  int tile = row >> 5, ks = oct >> 1, lane = ((oct & 1) << 5) | (row & 31);
  return (size_t)(tile * 8 + ks) * 64 + lane;
}

// K1: fused pack.
// Blocks [0,512): B-side — x2 + bf16 pack of 16 input rows.
// Blocks [512,1024): A-side — 2 classes/block: batch-load targets (all 32
// loads in flight BEFORE the LDS-atomic compare loop), member lists, gather
// center (16 loads in flight), c2, counts, bf16 pack. Block 0 zeroes out.
__global__ __launch_bounds__(256) void pack_kernel(
    const float* __restrict__ inputs, const int* __restrict__ targets,
    float* __restrict__ x2, float* __restrict__ c2, int* __restrict__ counts,
    short8* __restrict__ Apk, short8* __restrict__ Bpk, float* __restrict__ out) {
  int b = blockIdx.x;
  int tid = threadIdx.x;
  if (b == 0 && tid < 2) out[tid] = 0.f;
  if (b < N_SAMPLES / 16) {
    int row = b * 16 + (tid >> 4);
    int oct = tid & 15;
    const float4* p = (const float4*)(inputs + (size_t)row * DIM + oct * 8);
    float4 v0 = p[0], v1 = p[1];
    float v[8] = {v0.x, v0.y, v0.z, v0.w, v1.x, v1.y, v1.z, v1.w};
    float s = 0.f;
    #pragma unroll
    for (int i = 0; i < 8; i++) s += v[i] * v[i];
    #pragma unroll
    for (int m = 1; m < 16; m <<= 1) s += __shfl_xor(s, m);
    if (oct == 0) x2[row] = s;
    short8 hi;
    #pragma unroll
    for (int i = 0; i < 8; i++) hi[i] = bf16_rne(v[i]);
    Bpk[frag_idx(row, oct)] = hi;
  } else {
    __shared__ int mem[2][MAXMEM];
    __shared__ int mcnt[2];
    __shared__ float sctr[2][128];
    __shared__ float wsum[4];
    int c0 = (b - N_SAMPLES / 16) * 2;
    if (tid < 2) { mcnt[tid] = 0; mem[tid][0] = 0; }  // mem[.][0] valid even if cnt==0
    __syncthreads();
    // batch-load all targets first (independent loads, no atomic interleave)
    int tg[N_SAMPLES / 256];
    #pragma unroll
    for (int i = 0; i < N_SAMPLES / 256; i++) tg[i] = targets[tid + 256 * i];
    #pragma unroll
    for (int i = 0; i < N_SAMPLES / 256; i++) {
      if (tg[i] == c0) {
        int p = atomicAdd(&mcnt[0], 1);
        if (p < MAXMEM) mem[0][p] = tid + 256 * i;
      } else if (tg[i] == c0 + 1) {
        int p = atomicAdd(&mcnt[1], 1);
        if (p < MAXMEM) mem[1][p] = tid + 256 * i;
      }
    }
    __syncthreads();
    int half = tid >> 7;
    int c = c0 + half;
    int d = tid & 127;
    int cnt = mcnt[half];
    int cl = (cnt < MAXMEM) ? cnt : MAXMEM;
    int n1 = (cl < PIPE) ? cl : PIPE;
    int idxs[PIPE];
    #pragma unroll
    for (int i = 0; i < PIPE; i++) idxs[i] = mem[half][(i < n1) ? i : 0];
    float vbuf[PIPE];
    #pragma unroll
    for (int i = 0; i < PIPE; i++) vbuf[i] = inputs[(size_t)idxs[i] * DIM + d];
    float acc = 0.f;
    #pragma unroll
    for (int i = 0; i < PIPE; i++) if (i < n1) acc += vbuf[i];
    for (int m = PIPE; m < cl; m++) acc += inputs[(size_t)mem[half][m] * DIM + d];
    float ctr = (cnt > 0) ? acc / (float)cnt : 0.f;
    sctr[half][d] = ctr;
    float vv = ctr * ctr;
    #pragma unroll
    for (int sh = 32; sh > 0; sh >>= 1) vv += __shfl_down(vv, sh);
    if ((tid & 63) == 0) wsum[tid >> 6] = vv;
    __syncthreads();
    if (d == 0) {
      c2[c] = wsum[half * 2] + wsum[half * 2 + 1];
      counts[c] = cnt;
    }
    if (d < 16) {
      int oct = d;
      short8 hi;
      #pragma unroll
      for (int i = 0; i < 8; i++) hi[i] = bf16_rne(sctr[half][oct * 8 + i]);
      Apk[frag_idx(c, oct)] = hi;
    }
  }
}

// K2: MFMA dist, class-split occupancy version. Tile 64 classes x 128 j per
// block, grid (64,16) = 1024 blocks = 4 blocks/CU. Wave (wm,wn) owns m-tile
// wm (32 classes) x 2 n-tiles (64 j): acc = 2 x f32x16 = 32 VGPR; 3 loads +
// 2 MFMA per ks. __launch_bounds__(256,4) keeps VGPR <= 128 so 16 waves/CU
// actually fit -> 2x latency overlap vs R12's grid-capped 8 waves/CU.
__global__ __launch_bounds__(256, 4) void dist_kernel(
    const short8* __restrict__ Apk, const short8* __restrict__ Bpk,
    const float* __restrict__ x2, const float* __restrict__ c2,
    const int* __restrict__ targets,
    float* __restrict__ dp_part, float* __restrict__ dn_part) {
  __shared__ float sc2[64];
  __shared__ float sx2[128];
  __shared__ int stgt[128];
  __shared__ float redp[2][2][32];  // [wn][wm][class-in-tile]
  __shared__ float redn[2][2][32];

  int tid = threadIdx.x;
  int jbase = blockIdx.x * 128;
  int cbase = blockIdx.y * 64;
  int wave = tid >> 6, lane = tid & 63;
  int wm = wave >> 1, wn = wave & 1;

  if (tid < 128) {
    sx2[tid] = x2[jbase + tid];
    stgt[tid] = targets[jbase + tid];
  }
  if (tid < 64) sc2[tid] = c2[cbase + tid];

  int mtg = (cbase >> 5) + wm;       // this wave's m-tile in Apk
  int ntg0 = (jbase >> 5) + wn * 2;  // first of 2 n-tiles in Bpk

  f32x16 acc[2];
  acc[0] = (f32x16)(0.f);
  acc[1] = (f32x16)(0.f);

  #pragma unroll
  for (int ks = 0; ks < 8; ks++) {
    bf16x8 av = Apk[(size_t)(mtg * 8 + ks) * 64 + lane];
    bf16x8 b0 = Bpk[(size_t)((ntg0 + 0) * 8 + ks) * 64 + lane];
    bf16x8 b1 = Bpk[(size_t)((ntg0 + 1) * 8 + ks) * 64 + lane];
    acc[0] = __builtin_amdgcn_mfma_f32_32x32x16_bf16(av, b0, acc[0], 0, 0, 0);
    acc[1] = __builtin_amdgcn_mfma_f32_32x32x16_bf16(av, b1, acc[1], 0, 0, 0);
  }

  __syncthreads();  // staging visible

  int hf = lane >> 5;
  int col = lane & 31;
  #pragma unroll
  for (int r = 0; r < 16; r++) {
    int rowl = (r & 3) + 8 * (r >> 2) + 4 * hf;   // (r,hf) covers 0..31 once
    int c_loc = wm * 32 + rowl;
    int cg = cbase + c_loc;
    float c2v = sc2[c_loc];
    float pmax = -INFINITY, nmin = INFINITY;
    #pragma unroll
    for (int nt = 0; nt < 2; nt++) {
      int j_loc = wn * 64 + nt * 32 + col;
      float d2 = c2v + sx2[j_loc] - 2.f * acc[nt][r];
      if (stgt[j_loc] == cg) pmax = fmaxf(pmax, d2);
      else                   nmin = fminf(nmin, d2);
    }
    #pragma unroll
    for (int m = 1; m < 32; m <<= 1) {
      pmax = fmaxf(pmax, __shfl_xor(pmax, m));
      nmin = fminf(nmin, __shfl_xor(nmin, m));
    }
    if (col == 0) {  // lanes 0 (hf=0) and 32 (hf=1): distinct rowl
      redp[wn][wm][rowl] = pmax;
      redn[wn][wm][rowl] = nmin;
    }
  }
  __syncthreads();
  if (tid < 64) {  // one thread per class in this block's 64-class tile
    int wmx = tid >> 5, idx = tid & 31;
    float dp = fmaxf(redp[0][wmx][idx], redp[1][wmx][idx]);
    float dn = fminf(redn[0][wmx][idx], redn[1][wmx][idx]);
    size_t slot = (size_t)blockIdx.x * NCLS + cbase + tid;
    dp_part[slot] = dp;
    dn_part[slot] = dn;
  }
}

// K3: 16 blocks x 256 threads. Block g owns 64 classes; 4 p-groups x 16
// partials each, coalesced reads (32 KB/block), LDS combine, weighted wave
// reduce, one atomicAdd pair per block into out (zeroed by K1).
__global__ __launch_bounds__(256) void finalize_kernel(
    const float* __restrict__ dp_part, const float* __restrict__ dn_part,
    const int* __restrict__ counts, float* __restrict__ out) {
  __shared__ float sdp[4][64];
  __shared__ float sdn[4][64];
  int g = blockIdx.x;
  int t = threadIdx.x;
  int cl = t & 63;
  int pg = t >> 6;
  int c = g * 64 + cl;
  float dp = -INFINITY, dn = INFINITY;
  #pragma unroll
  for (int p = pg * 16; p < pg * 16 + 16; p++) {
    dp = fmaxf(dp, dp_part[(size_t)p * NCLS + c]);
    dn = fminf(dn, dn_part[(size_t)p * NCLS + c]);
  }
  sdp[pg][cl] = dp;
  sdn[pg][cl] = dn;
  __syncthreads();
  if (t < 64) {  // wave 0
    dp = fmaxf(fmaxf(sdp[0][cl], sdp[1][cl]), fmaxf(sdp[2][cl], sdp[3][cl]));
    dn = fminf(fminf(sdn[0][cl], sdn[1][cl]), fminf(sdn[2][cl], sdn[3][cl]));
    int cnt = counts[c];
    float ls = 0.f, ps = 0.f;
    if (cnt > 0) {
      ls = (float)cnt * fmaxf(dp - dn + MARGIN_V, 0.f);
      ps = (float)cnt * ((dn > dp) ? 1.f : 0.f);
    }
    #pragma unroll
    for (int sh = 32; sh > 0; sh >>= 1) {
      ls += __shfl_down(ls, sh);
      ps += __shfl_down(ps, sh);
    }
    if (t == 0) {
      atomicAdd(&out[0], ls / (float)N_SAMPLES);
      atomicAdd(&out[1], ps / (float)N_SAMPLES);
    }
  }
}

extern "C" void kernel_launch(void* const* d_in, const int* in_sizes, int n_in,
                              void* d_out, int out_size, void* d_ws, size_t ws_size,
                              hipStream_t stream) {
  const float* inputs = (const float*)d_in[0];
  const int* targets = (const int*)d_in[1];
  float* out = (float*)d_out;

  char* w = (char*)d_ws;
  float* x2 = (float*)w;            w += (size_t)N_SAMPLES * 4;
  float* c2 = (float*)w;            w += (size_t)NCLS * 4;
  int* counts = (int*)w;            w += (size_t)NCLS * 4;
  float* dp_part = (float*)w;       w += (size_t)NPART * NCLS * 4;    // 256 KB
  float* dn_part = (float*)w;       w += (size_t)NPART * NCLS * 4;    // 256 KB
  short8* Apk = (short8*)w;         w += (size_t)NCLS * DIM * 2;      // 256 KB
  short8* Bpk = (short8*)w;         w += (size_t)N_SAMPLES * DIM * 2; // 2 MB

  pack_kernel<<<N_SAMPLES / 16 + NCLS / 2, 256, 0, stream>>>(
      inputs, targets, x2, c2, counts, Apk, Bpk, out);
  dist_kernel<<<dim3(DIST_GX, DIST_GY), 256, 0, stream>>>(
      Apk, Bpk, x2, c2, targets, dp_part, dn_part);
  finalize_kernel<<<16, 256, 0, stream>>>(dp_part, dn_part, counts, out);
}